// Round 1
// baseline (1094.844 us; speedup 1.0000x reference)
//
#include <hip/hip_runtime.h>
#include <hip/hip_bf16.h>

// Problem constants
#define PB 8
#define PS 1024
#define PD 512
#define PH 8
#define PDH 64

// ---------------------------------------------------------------------------
// GEMM: out[m,n] = sum_k X[m,k] * W[n,k] + bias[n]
// X: [8192, 512] row-major, W: [512, 512] row-major (einsum "bsd,ed->bse")
// out_mode 0: out[m*512 + n]
// out_mode 1: head-split -> out[((b*8 + n>>6)*1024 + s)*64 + (n&63)], m=b*1024+s
// ---------------------------------------------------------------------------
__global__ __launch_bounds__(256)
void gemm_nt(const float* __restrict__ X, const float* __restrict__ W,
             const float* __restrict__ bias, float* __restrict__ out,
             int out_mode)
{
    __shared__ __align__(16) float As[32][68];
    __shared__ __align__(16) float Bs[32][68];
    const int tid = threadIdx.x;
    const int bm = blockIdx.x * 64;
    const int bn = blockIdx.y * 64;
    const int tm = tid >> 4;   // 0..15
    const int tn = tid & 15;   // 0..15

    float acc[4][4];
#pragma unroll
    for (int r = 0; r < 4; ++r)
#pragma unroll
        for (int c = 0; c < 4; ++c) acc[r][c] = 0.f;

    for (int k0 = 0; k0 < 512; k0 += 32) {
#pragma unroll
        for (int rr = 0; rr < 2; ++rr) {
            const int idx = rr * 256 + tid;     // 0..511
            const int row = idx >> 3;           // 0..63
            const int kg  = idx & 7;            // float4 index in 32 k's
            const float4 a = *(const float4*)(X + (size_t)(bm + row) * 512 + k0 + kg * 4);
            As[kg*4+0][row] = a.x; As[kg*4+1][row] = a.y;
            As[kg*4+2][row] = a.z; As[kg*4+3][row] = a.w;
            const float4 bb = *(const float4*)(W + (size_t)(bn + row) * 512 + k0 + kg * 4);
            Bs[kg*4+0][row] = bb.x; Bs[kg*4+1][row] = bb.y;
            Bs[kg*4+2][row] = bb.z; Bs[kg*4+3][row] = bb.w;
        }
        __syncthreads();
#pragma unroll
        for (int k = 0; k < 32; ++k) {
            const float4 a = *(const float4*)&As[k][tm * 4];
            const float4 b = *(const float4*)&Bs[k][tn * 4];
            const float av[4] = {a.x, a.y, a.z, a.w};
            const float bv[4] = {b.x, b.y, b.z, b.w};
#pragma unroll
            for (int r = 0; r < 4; ++r)
#pragma unroll
                for (int c = 0; c < 4; ++c)
                    acc[r][c] = fmaf(av[r], bv[c], acc[r][c]);
        }
        __syncthreads();
    }

#pragma unroll
    for (int r = 0; r < 4; ++r) {
        const int m = bm + tm * 4 + r;
        const int b = m >> 10, s = m & 1023;
#pragma unroll
        for (int c = 0; c < 4; ++c) {
            const int n = bn + tn * 4 + c;
            const float v = acc[r][c] + bias[n];
            if (out_mode == 0)
                out[(size_t)m * 512 + n] = v;
            else
                out[(((size_t)b * 8 + (n >> 6)) * 1024 + s) * 64 + (n & 63)] = v;
        }
    }
}

// ---------------------------------------------------------------------------
// Fused attention: one workgroup = 16 waves = 16 query rows of one (b,h).
// Wave w handles row i = qb*16 + w; lane j holds logit chunk elements.
// LDS K/V tile 64x64 f32 with 16B-slot XOR swizzle (conflict-free b128 reads).
// ---------------------------------------------------------------------------
__global__ __launch_bounds__(1024)
void attn_kernel(const float* __restrict__ qh, const float* __restrict__ kh,
                 const float* __restrict__ vh, const float* __restrict__ gammas,
                 float* __restrict__ scores_out, float* __restrict__ attn_out)
{
    const int bh   = blockIdx.y;          // 0..63
    const int h    = bh & 7;
    const int b    = bh >> 3;
    const int qb   = blockIdx.x;          // 0..63
    const int i0   = qb * 16;
    const int wave = threadIdx.x >> 6;    // 0..15
    const int lane = threadIdx.x & 63;
    const int i    = i0 + wave;           // query row
    const int T    = i0 / 64 + 1;         // key tiles needed (uniform in block)

    __shared__ __align__(16) float q_lds[16][64];
    __shared__ __align__(16) float kv_lds[64][64];
    __shared__ __align__(16) float s2_lds[16][64];

    q_lds[wave][lane] = qh[((size_t)bh * PS + i) * 64 + lane];
    __syncthreads();

    const float gamma = -fabsf(gammas[h]);

    float l[16], cum[16];
#pragma unroll
    for (int c = 0; c < 16; ++c) { l[c] = -3.0e38f; cum[c] = 0.f; }

    // staging decomposition: 1024 threads load 64 keys x 16 float4 each tile
    const int sj = threadIdx.x >> 4;             // key row 0..63
    const int sd = threadIdx.x & 15;             // float4 slot 0..15
    const int sslot = sd ^ (sj & 15);            // XOR swizzle

    // ---------------- Pass A: logits ----------------
#pragma unroll
    for (int t = 0; t < 16; ++t) {
        if (t >= T) break;
        {
            const float4 kv = *(const float4*)(kh + ((size_t)bh * PS + t * 64 + sj) * 64 + sd * 4);
            *(float4*)&kv_lds[sj][sslot * 4] = kv;
        }
        __syncthreads();
        float acc = 0.f;
#pragma unroll
        for (int d4 = 0; d4 < 16; ++d4) {
            const float4 kj = *(const float4*)&kv_lds[lane][(d4 ^ (lane & 15)) * 4];
            const float4 qd = *(const float4*)&q_lds[wave][d4 * 4];
            acc = fmaf(qd.x, kj.x, acc);
            acc = fmaf(qd.y, kj.y, acc);
            acc = fmaf(qd.z, kj.z, acc);
            acc = fmaf(qd.w, kj.w, acc);
        }
        const int jg = t * 64 + lane;
        l[t] = (jg <= i) ? acc * 0.125f : -3.0e38f;
        __syncthreads();
    }

    // ---------------- softmax 1 (over j<=i) ----------------
    float m1 = -3.0e38f;
#pragma unroll
    for (int c = 0; c < 16; ++c) { if (c >= T) break; m1 = fmaxf(m1, l[c]); }
#pragma unroll
    for (int off = 32; off > 0; off >>= 1) m1 = fmaxf(m1, __shfl_xor(m1, off));

    float es = 0.f;
#pragma unroll
    for (int c = 0; c < 16; ++c) { if (c >= T) break; es += expf(l[c] - m1); }
#pragma unroll
    for (int off = 32; off > 0; off >>= 1) es += __shfl_xor(es, off);
    const float inv1 = 1.0f / es;

    // ---------------- cumsum (inclusive, left-to-right) ----------------
    float run = 0.f;
#pragma unroll
    for (int c = 0; c < 16; ++c) {
        if (c >= T) break;
        float x = expf(l[c] - m1) * inv1;
#pragma unroll
        for (int off = 1; off < 64; off <<= 1) {
            const float y = __shfl_up(x, off);
            if (lane >= off) x += y;
        }
        cum[c] = run + x;
        run += __shfl(x, 63);
    }
    const float dt = run;   // disttotal (sum of normalized row)

    // ---------------- distance-decay effect, modified logits ----------------
#pragma unroll
    for (int c = 0; c < 16; ++c) {
        if (c >= T) break;
        const int jg = c * 64 + lane;
        const float pe = fabsf((float)(i - jg));
        const float r = fmaxf(dt - cum[c], 0.f);
        const float dist = sqrtf(r * pe);
        const float eff = fmaxf(expf(gamma * dist), 1e-5f);
        l[c] = l[c] * eff;   // masked stays <= -3e33 -> exp underflows to 0
    }

    // ---------------- softmax 2 ----------------
    float m2 = -3.0e38f;
#pragma unroll
    for (int c = 0; c < 16; ++c) { if (c >= T) break; m2 = fmaxf(m2, l[c]); }
#pragma unroll
    for (int off = 32; off > 0; off >>= 1) m2 = fmaxf(m2, __shfl_xor(m2, off));

    float es2 = 0.f;
#pragma unroll
    for (int c = 0; c < 16; ++c) { if (c >= T) break; es2 += expf(l[c] - m2); }
#pragma unroll
    for (int off = 32; off > 0; off >>= 1) es2 += __shfl_xor(es2, off);
    const float inv2 = 1.0f / es2;

#pragma unroll
    for (int c = 0; c < 16; ++c) { if (c >= T) break; l[c] = expf(l[c] - m2) * inv2; }

    // ---------------- write scores row (zeros above diagonal) ----------------
    float* srow = scores_out + ((size_t)bh * PS + i) * PS;
#pragma unroll
    for (int c = 0; c < 16; ++c)
        srow[c * 64 + lane] = (c < T) ? l[c] : 0.f;

    // ---------------- Pass B: PV ----------------
    float oacc = 0.f;
#pragma unroll
    for (int t = 0; t < 16; ++t) {
        if (t >= T) break;
        {
            const float4 vv = *(const float4*)(vh + ((size_t)bh * PS + t * 64 + sj) * 64 + sd * 4);
            *(float4*)&kv_lds[sj][sslot * 4] = vv;
        }
        __syncthreads();
        s2_lds[wave][lane] = l[t];
#pragma unroll
        for (int jj = 0; jj < 64; ++jj) {
            const float sv = s2_lds[wave][jj];
            const float vj = kv_lds[jj][(((lane >> 2) ^ (jj & 15)) << 2) + (lane & 3)];
            oacc = fmaf(sv, vj, oacc);
        }
        __syncthreads();
    }

    // concat layout [b, s, h, dh] -> [8192, 512] for the output GEMM
    attn_out[(((size_t)b * PS + i) * 8 + h) * 64 + lane] = oacc;
}

// ---------------------------------------------------------------------------
extern "C" void kernel_launch(void* const* d_in, const int* in_sizes, int n_in,
                              void* d_out, int out_size, void* d_ws, size_t ws_size,
                              hipStream_t stream)
{
    const float* q      = (const float*)d_in[0];
    const float* k      = (const float*)d_in[1];
    const float* v      = (const float*)d_in[2];
    // d_in[3] is the causal mask (tril) -- structure known, not read
    const float* Wq     = (const float*)d_in[4];
    const float* bq     = (const float*)d_in[5];
    const float* Wv     = (const float*)d_in[6];
    const float* bv     = (const float*)d_in[7];
    const float* Wo     = (const float*)d_in[8];
    const float* bo     = (const float*)d_in[9];
    const float* gammas = (const float*)d_in[10];

    float* out    = (float*)d_out;                       // [8,1024,512]
    float* scores = out + (size_t)PB * PS * PD;          // [8,8,1024,1024]

    float* ws   = (float*)d_ws;
    float* qh   = ws;                   // [64,1024,64] = 16MB
    float* khp  = ws + 4194304;         // 16MB
    float* vhp  = ws + 8388608;         // 16MB
    float* attn = ws + 12582912;        // 16MB

    const dim3 gblk(256);
    const dim3 ggrid(128, 8);           // M/64 x N/64

    gemm_nt<<<ggrid, gblk, 0, stream>>>(q, Wq, bq, qh, 1);
    gemm_nt<<<ggrid, gblk, 0, stream>>>(k, Wq, bq, khp, 1);
    gemm_nt<<<ggrid, gblk, 0, stream>>>(v, Wv, bv, vhp, 1);

    attn_kernel<<<dim3(64, 64), 1024, 0, stream>>>(qh, khp, vhp, gammas, scores, attn);

    gemm_nt<<<ggrid, gblk, 0, stream>>>(attn, Wo, bo, out, 0);
}

// Round 2
// 280.937 us; speedup vs baseline: 3.8971x; 3.8971x over previous
//
#include <hip/hip_runtime.h>
#include <hip/hip_bf16.h>

#define PB 8
#define PS 1024
#define PD 512
#define PH 8

typedef __attribute__((ext_vector_type(8))) short short8;
typedef __attribute__((ext_vector_type(4))) float f32x4;

__device__ inline ushort f2bf(float x) {
    union { float f; unsigned u; } c; c.f = x;
    unsigned u = c.u + 0x7fffu + ((c.u >> 16) & 1u);
    return (ushort)(u >> 16);
}

__device__ inline void gload16(const void* g, void* l) {
    __builtin_amdgcn_global_load_lds(
        (const __attribute__((address_space(1))) void*)g,
        (__attribute__((address_space(3))) void*)l, 16, 0, 0);
}

// ---------------------------------------------------------------------------
__global__ __launch_bounds__(256)
void cast_bf16(const float* __restrict__ s, ushort* __restrict__ d, int n4)
{
    const int i = blockIdx.x * 256 + threadIdx.x;
    if (i >= n4) return;
    const float4 v = ((const float4*)s)[i];
    ushort4 o;
    o.x = f2bf(v.x); o.y = f2bf(v.y); o.z = f2bf(v.z); o.w = f2bf(v.w);
    ((ushort4*)d)[i] = o;
}

// ---------------------------------------------------------------------------
// NT GEMM: out[m,n] = sum_k A[m,k]*B[n,k] + bias[n].  A:[M][K] bf16, B:[N][K] bf16.
// MODE 0: f32 out[m*N+n].  MODE 1: bf16 head-split [(b*8+h)*1024+s][64].
// 128x128 tile, BK=64, 256 threads (4 waves, 2x2), mfma 16x16x32 bf16.
// ---------------------------------------------------------------------------
template<int MODE>
__global__ __launch_bounds__(256)
void gemm_mfma(const ushort* __restrict__ A, const ushort* __restrict__ B,
               const float* __restrict__ bias, void* __restrict__ out,
               int M, int N, int K)
{
    __shared__ __align__(16) ushort As[128 * 64];
    __shared__ __align__(16) ushort Bs[128 * 64];
    const int tid = threadIdx.x;
    const int lane = tid & 63;
    const int wave = tid >> 6;
    const int wr = wave >> 1, wc = wave & 1;
    const int bm = blockIdx.x * 128, bn = blockIdx.y * 128;
    const int lrow = lane >> 3;          // row within 8-row chunk
    const int lcol = (lane & 7) * 8;     // elem col within 64

    f32x4 acc[4][4] = {};

    for (int k0 = 0; k0 < K; k0 += 64) {
#pragma unroll
        for (int i = 0; i < 4; ++i) {
            const int c = wave * 4 + i;  // chunk 0..15 = rows c*8..c*8+7
            gload16(A + (size_t)(bm + c * 8 + lrow) * K + k0 + lcol, &As[c * 512]);
            gload16(B + (size_t)(bn + c * 8 + lrow) * K + k0 + lcol, &Bs[c * 512]);
        }
        __syncthreads();
        short8 af[2][4], bf[2][4];
#pragma unroll
        for (int kk = 0; kk < 2; ++kk) {
#pragma unroll
            for (int m = 0; m < 4; ++m)
                af[kk][m] = *(const short8*)&As[(wr * 64 + m * 16 + (lane & 15)) * 64 + kk * 32 + (lane >> 4) * 8];
#pragma unroll
            for (int n = 0; n < 4; ++n)
                bf[kk][n] = *(const short8*)&Bs[(wc * 64 + n * 16 + (lane & 15)) * 64 + kk * 32 + (lane >> 4) * 8];
        }
#pragma unroll
        for (int kk = 0; kk < 2; ++kk)
#pragma unroll
            for (int m = 0; m < 4; ++m)
#pragma unroll
                for (int n = 0; n < 4; ++n)
                    acc[m][n] = __builtin_amdgcn_mfma_f32_16x16x32_bf16(af[kk][m], bf[kk][n], acc[m][n], 0, 0, 0);
        __syncthreads();
    }

#pragma unroll
    for (int m = 0; m < 4; ++m)
#pragma unroll
        for (int n = 0; n < 4; ++n)
#pragma unroll
            for (int r = 0; r < 4; ++r) {
                const int row = bm + wr * 64 + m * 16 + (lane >> 4) * 4 + r;
                const int col = bn + wc * 64 + n * 16 + (lane & 15);
                const float v = acc[m][n][r] + bias[col];
                if (MODE == 0) {
                    ((float*)out)[(size_t)row * N + col] = v;
                } else {
                    const int b = row >> 10, s = row & 1023;
                    const int h = col >> 6, d = col & 63;
                    ((ushort*)out)[(((size_t)(b * 8 + h)) * 1024 + s) * 64 + d] = f2bf(v);
                }
            }
}

// ---------------------------------------------------------------------------
// QK^T per (b,h): logits[q,k] = 0.125 * sum_d Q[q,d]*K[k,d]. 128x128 block,
// K-dim = 64 (one stage). Upper-triangular blocks skipped (never read later).
// ---------------------------------------------------------------------------
__global__ __launch_bounds__(256)
void qk_mfma(const ushort* __restrict__ qh, const ushort* __restrict__ kh,
             float* __restrict__ scores)
{
    const int kb = blockIdx.x, qb = blockIdx.y, bh = blockIdx.z;
    if (kb > qb) return;
    __shared__ __align__(16) ushort As[128 * 64];
    __shared__ __align__(16) ushort Bs[128 * 64];
    const int tid = threadIdx.x, lane = tid & 63, wave = tid >> 6;
    const int wr = wave >> 1, wc = wave & 1;
    const ushort* Ab = qh + ((size_t)bh * PS + qb * 128) * 64;  // contiguous 16KB
    const ushort* Bb = kh + ((size_t)bh * PS + kb * 128) * 64;

#pragma unroll
    for (int i = 0; i < 4; ++i) {
        const int c = wave * 4 + i;
        gload16(Ab + c * 512 + lane * 8, &As[c * 512]);
        gload16(Bb + c * 512 + lane * 8, &Bs[c * 512]);
    }
    __syncthreads();

    f32x4 acc[4][4] = {};
    short8 af[2][4], bf[2][4];
#pragma unroll
    for (int kk = 0; kk < 2; ++kk) {
#pragma unroll
        for (int m = 0; m < 4; ++m)
            af[kk][m] = *(const short8*)&As[(wr * 64 + m * 16 + (lane & 15)) * 64 + kk * 32 + (lane >> 4) * 8];
#pragma unroll
        for (int n = 0; n < 4; ++n)
            bf[kk][n] = *(const short8*)&Bs[(wc * 64 + n * 16 + (lane & 15)) * 64 + kk * 32 + (lane >> 4) * 8];
    }
#pragma unroll
    for (int kk = 0; kk < 2; ++kk)
#pragma unroll
        for (int m = 0; m < 4; ++m)
#pragma unroll
            for (int n = 0; n < 4; ++n)
                acc[m][n] = __builtin_amdgcn_mfma_f32_16x16x32_bf16(af[kk][m], bf[kk][n], acc[m][n], 0, 0, 0);

    float* S = scores + ((size_t)bh << 20);
#pragma unroll
    for (int m = 0; m < 4; ++m)
#pragma unroll
        for (int n = 0; n < 4; ++n)
#pragma unroll
            for (int r = 0; r < 4; ++r) {
                const int row = qb * 128 + wr * 64 + m * 16 + (lane >> 4) * 4 + r;
                const int col = kb * 128 + wc * 64 + n * 16 + (lane & 15);
                S[(size_t)row * 1024 + col] = acc[m][n][r] * 0.125f;
            }
}

// ---------------------------------------------------------------------------
// Row pass: one wave per query row. softmax1 -> cumsum -> decay -> softmax2.
// In-place on the scores buffer; writes zeros above the diagonal.
// ---------------------------------------------------------------------------
__global__ __launch_bounds__(1024)
void row_pass(float* __restrict__ scores, const float* __restrict__ gammas)
{
    const int bh = blockIdx.y, h = bh & 7;
    const int i = blockIdx.x * 16 + (threadIdx.x >> 6);
    const int lane = threadIdx.x & 63;
    float* row = scores + ((size_t)bh << 20) + ((size_t)i << 10);
    const int j0 = lane * 16;
    const int nv = min(max(i + 1 - j0, 0), 16);   // valid elems in this lane
    const float gamma = -fabsf(gammas[h]);

    float l[16];
    if (nv > 0) {
#pragma unroll
        for (int c = 0; c < 4; ++c) {
            const float4 v = *(const float4*)&row[j0 + c * 4];
            l[c * 4 + 0] = v.x; l[c * 4 + 1] = v.y; l[c * 4 + 2] = v.z; l[c * 4 + 3] = v.w;
        }
    } else {
#pragma unroll
        for (int c = 0; c < 16; ++c) l[c] = 0.f;
    }

    // softmax-1 max
    float m1 = -3.0e38f;
#pragma unroll
    for (int c = 0; c < 16; ++c) if (c < nv) m1 = fmaxf(m1, l[c]);
#pragma unroll
    for (int off = 32; off; off >>= 1) m1 = fmaxf(m1, __shfl_xor(m1, off));

    // exp + in-lane inclusive cumsum
    float cum[16];
    float csum = 0.f;
#pragma unroll
    for (int c = 0; c < 16; ++c) {
        const float e = (c < nv) ? __expf(l[c] - m1) : 0.f;
        csum += e;
        cum[c] = csum;
    }
    // wave scan of lane totals
    float incl = csum;
#pragma unroll
    for (int off = 1; off < 64; off <<= 1) {
        const float y = __shfl_up(incl, off);
        if (lane >= off) incl += y;
    }
    const float excl = incl - csum;
    const float es = __shfl(incl, 63);
    const float inv_es = 1.0f / es;

    // distance-decay on raw logits, then softmax-2 max
    float m2 = -3.0e38f;
#pragma unroll
    for (int c = 0; c < 16; ++c) {
        if (c < nv) {
            const float pe = (float)(i - (j0 + c));                 // |i-j|, j<=i
            const float sfx = fmaxf((es - (excl + cum[c])) * inv_es, 0.f);
            const float dist = sqrtf(sfx * pe);
            const float eff = fmaxf(__expf(gamma * dist), 1e-5f);
            l[c] = l[c] * eff;
            m2 = fmaxf(m2, l[c]);
        }
    }
#pragma unroll
    for (int off = 32; off; off >>= 1) m2 = fmaxf(m2, __shfl_xor(m2, off));

    float s2 = 0.f;
#pragma unroll
    for (int c = 0; c < 16; ++c) {
        if (c < nv) { l[c] = __expf(l[c] - m2); s2 += l[c]; }
        else l[c] = 0.f;
    }
#pragma unroll
    for (int off = 32; off; off >>= 1) s2 += __shfl_xor(s2, off);
    const float inv2 = 1.0f / s2;

#pragma unroll
    for (int c = 0; c < 4; ++c) {
        float4 v;
        v.x = l[c * 4 + 0] * inv2; v.y = l[c * 4 + 1] * inv2;
        v.z = l[c * 4 + 2] * inv2; v.w = l[c * 4 + 3] * inv2;
        *(float4*)&row[j0 + c * 4] = v;
    }
}

// ---------------------------------------------------------------------------
// PV per (b,h): O[q,d] = sum_k P[q,k]*V[k,d]. P staged f32->bf16; V via
// global_load_lds. BM=128, BN=64, BK=64; wave tile 64x32. Causal K-loop.
// ---------------------------------------------------------------------------
__global__ __launch_bounds__(256)
void pv_mfma(const float* __restrict__ scores, const ushort* __restrict__ vh,
             ushort* __restrict__ attn)
{
    const int qb = blockIdx.x, bh = blockIdx.y;
    const int b = bh >> 3, h = bh & 7;
    __shared__ __align__(16) ushort As[128 * 64];
    __shared__ __align__(16) ushort Bs[64 * 64];
    const int tid = threadIdx.x, lane = tid & 63, wave = tid >> 6;
    const int wr = wave >> 1, wc = wave & 1;   // wave tile: 64 rows x 32 cols
    const int bm = qb * 128;
    const float* Sb = scores + ((size_t)bh << 20);
    const ushort* Vb = vh + ((size_t)bh << 16);

    f32x4 acc[4][2] = {};
    const int nt = 2 * qb + 2;                 // k-tiles up to diagonal
    for (int t = 0; t < nt; ++t) {
        // stage P tile [128 q][64 k] with f32->bf16 convert
#pragma unroll
        for (int ii = 0; ii < 4; ++ii) {
            const int flat = ii * 2048 + tid * 8;
            const int r = flat >> 6, cc = flat & 63;
            const float* src = Sb + (size_t)(bm + r) * 1024 + t * 64 + cc;
            const float4 x = *(const float4*)src;
            const float4 y = *(const float4*)(src + 4);
            union { ushort u[8]; uint4 v; } pk;
            pk.u[0] = f2bf(x.x); pk.u[1] = f2bf(x.y); pk.u[2] = f2bf(x.z); pk.u[3] = f2bf(x.w);
            pk.u[4] = f2bf(y.x); pk.u[5] = f2bf(y.y); pk.u[6] = f2bf(y.z); pk.u[7] = f2bf(y.w);
            *(uint4*)&As[flat] = pk.v;
        }
        // stage V tile [64 k][64 d]
#pragma unroll
        for (int ii = 0; ii < 2; ++ii) {
            const int c = wave * 2 + ii;
            gload16(Vb + (size_t)(t * 64 + c * 8 + (lane >> 3)) * 64 + (lane & 7) * 8, &Bs[c * 512]);
        }
        __syncthreads();

        short8 af[2][4], bfr[2][2];
#pragma unroll
        for (int kk = 0; kk < 2; ++kk) {
#pragma unroll
            for (int m = 0; m < 4; ++m)
                af[kk][m] = *(const short8*)&As[(wr * 64 + m * 16 + (lane & 15)) * 64 + kk * 32 + (lane >> 4) * 8];
#pragma unroll
            for (int n = 0; n < 2; ++n) {
                short8 bb;
#pragma unroll
                for (int j = 0; j < 8; ++j)   // column read of V (no transpose stored)
                    bb[j] = (short)Bs[(kk * 32 + (lane >> 4) * 8 + j) * 64 + wc * 32 + n * 16 + (lane & 15)];
                bfr[kk][n] = bb;
            }
        }
#pragma unroll
        for (int kk = 0; kk < 2; ++kk)
#pragma unroll
            for (int m = 0; m < 4; ++m)
#pragma unroll
                for (int n = 0; n < 2; ++n)
                    acc[m][n] = __builtin_amdgcn_mfma_f32_16x16x32_bf16(af[kk][m], bfr[kk][n], acc[m][n], 0, 0, 0);
        __syncthreads();
    }

#pragma unroll
    for (int m = 0; m < 4; ++m)
#pragma unroll
        for (int n = 0; n < 2; ++n)
#pragma unroll
            for (int r = 0; r < 4; ++r) {
                const int srow = bm + wr * 64 + m * 16 + (lane >> 4) * 4 + r;
                const int d = wc * 32 + n * 16 + (lane & 15);
                attn[(((size_t)b * 1024 + srow) * 8 + h) * 64 + d] = f2bf(acc[m][n][r]);
            }
}

// ---------------------------------------------------------------------------
extern "C" void kernel_launch(void* const* d_in, const int* in_sizes, int n_in,
                              void* d_out, int out_size, void* d_ws, size_t ws_size,
                              hipStream_t stream)
{
    const float* q      = (const float*)d_in[0];
    const float* k      = (const float*)d_in[1];
    const float* v      = (const float*)d_in[2];
    const float* Wq     = (const float*)d_in[4];
    const float* bq     = (const float*)d_in[5];
    const float* Wv     = (const float*)d_in[6];
    const float* bv     = (const float*)d_in[7];
    const float* Wo     = (const float*)d_in[8];
    const float* bo     = (const float*)d_in[9];
    const float* gammas = (const float*)d_in[10];

    float* out    = (float*)d_out;                       // [8,1024,512] f32
    float* scores = out + (size_t)PB * PS * PD;          // [64,1024,1024] f32

    char* w = (char*)d_ws;
    ushort* q_bf  = (ushort*)(w);                        // 8 MB each
    ushort* k_bf  = (ushort*)(w + (8u  << 20));
    ushort* v_bf  = (ushort*)(w + (16u << 20));
    ushort* Wq_bf = (ushort*)(w + (24u << 20));          // 0.5 MB each
    ushort* Wv_bf = (ushort*)(w + (25u << 20));
    ushort* Wo_bf = (ushort*)(w + (26u << 20));
    ushort* qh    = (ushort*)(w + (27u << 20));          // 8 MB each
    ushort* kh    = (ushort*)(w + (35u << 20));
    ushort* vh    = (ushort*)(w + (43u << 20));
    ushort* attn  = (ushort*)(w + (51u << 20));          // 8 MB

    cast_bf16<<<4096, 256, 0, stream>>>(q, q_bf, 1048576);
    cast_bf16<<<4096, 256, 0, stream>>>(k, k_bf, 1048576);
    cast_bf16<<<4096, 256, 0, stream>>>(v, v_bf, 1048576);
    cast_bf16<<<256, 256, 0, stream>>>(Wq, Wq_bf, 65536);
    cast_bf16<<<256, 256, 0, stream>>>(Wv, Wv_bf, 65536);
    cast_bf16<<<256, 256, 0, stream>>>(Wo, Wo_bf, 65536);

    gemm_mfma<1><<<dim3(64, 4), 256, 0, stream>>>(q_bf, Wq_bf, bq, qh, 8192, 512, 512);
    gemm_mfma<1><<<dim3(64, 4), 256, 0, stream>>>(k_bf, Wq_bf, bq, kh, 8192, 512, 512);
    gemm_mfma<1><<<dim3(64, 4), 256, 0, stream>>>(v_bf, Wv_bf, bv, vh, 8192, 512, 512);

    qk_mfma<<<dim3(8, 8, 64), 256, 0, stream>>>(qh, kh, scores);
    row_pass<<<dim3(64, 64), 1024, 0, stream>>>(scores, gammas);
    pv_mfma<<<dim3(8, 64), 256, 0, stream>>>(scores, vh, attn);

    gemm_mfma<0><<<dim3(64, 4), 256, 0, stream>>>(attn, Wo_bf, bo, out, 8192, 512, 512);
}